// Round 2
// baseline (520.148 us; speedup 1.0000x reference)
//
#include <hip/hip_runtime.h>

// NeRF fused render, MI355X. B=16384 rays x S=64 samples, MLP 3->256->256->256->4.
// Structure: 1 ray = 1 wave (64 samples); block = 4 waves = 4 rays; grid = 4096.
// MFMA 32x32x16 bf16, D = W^T x h^T: rows = hidden-n, cols = samples.
// LDS 160KB/block: 4 x 32KB wave-private h-fragments + 2 x 16KB double-buffered W stage.
// Weight pipeline: 17 tiles (W2 x8, W3 x8, W4 x1), reg-staged one tile ahead,
// ds_write to idle buffer overlaps MFMA on live buffer; ONE barrier per tile.
// LDS-budget arithmetic: per st-window (1033 cyc MFMA at 1 wave/SIMD):
//   wf reads 4x16KB + stage writes 16KB + h-repack 16KB + hf amortized 16KB
//   = ~112KB -> ~108 B/cyc vs 128 B/cyc LDS peak. MFMA-bound by design.

#define HID 256

typedef short bf16x8 __attribute__((ext_vector_type(8)));
typedef float f32x4  __attribute__((ext_vector_type(4)));
typedef float f32x16 __attribute__((ext_vector_type(16)));
typedef int   i32x4  __attribute__((ext_vector_type(4)));
typedef int   i32x2  __attribute__((ext_vector_type(2)));

static __device__ __forceinline__ unsigned short f2bf(float f) {
    unsigned u = __float_as_uint(f);
    u += 0x7fffu + ((u >> 16) & 1u);   // round-to-nearest-even
    return (unsigned short)(u >> 16);
}

// Fragment order for A(weights) and B(h): [tile][kt 16][lane 64][e 8],
// element = W[k = kt*16 + 8*(lane>>5) + e][n = nt*32 + (lane&31)].
// Both operands + the D->B repack use the same slot map, so the true HW k-map
// cancels; only the (verified) D layout formula matters.
__global__ void prep_pack(const float* __restrict__ W2, const float* __restrict__ W3,
                          const float* __restrict__ W4,
                          unsigned short* __restrict__ W2p, unsigned short* __restrict__ W3p,
                          unsigned short* __restrict__ W4p) {
    int t = blockIdx.x * 256 + threadIdx.x;
    if (t < 65536) {
        int e  = t & 7;
        int l  = (t >> 3) & 63;
        int kt = (t >> 9) & 15;
        int nt = t >> 13;
        int k = kt * 16 + 8 * (l >> 5) + e;
        int n = nt * 32 + (l & 31);
        W2p[t] = f2bf(W2[k * HID + n]);
        W3p[t] = f2bf(W3[k * HID + n]);
    } else if (t < 65536 + 8192) {
        int u  = t - 65536;
        int e  = u & 7;
        int l  = (u >> 3) & 63;
        int kt = u >> 9;
        int k = kt * 16 + 8 * (l >> 5) + e;
        int n = l & 31;                        // cols 0..3 real, 4..31 zero pad
        W4p[u] = f2bf((n < 4) ? W4[k * 4 + n] : 0.0f);
    }
}

static __device__ __forceinline__ float decode_scalar(const unsigned* __restrict__ p) {
    unsigned w0 = p[0];
    if (w0 == 0u) {                        // 0, or low word of a float64
        unsigned w1 = p[1];
        if (w1 != 0u) return (float)__hiloint2double((int)w1, (int)w0);
        return 0.0f;
    }
    if (w0 < 0x00800000u) return (float)(int)w0;   // small int32/int64
    return __uint_as_float(w0);                    // float32 bits
}

// One 256->256 layer over 8 weight tiles (nt = st). On entry: buf[0] holds this
// layer's tile0, sreg holds tile1. On exit: buf[0] holds next chain tile (tile8),
// sreg holds tile9. One __syncthreads per tile.
static __device__ __forceinline__ void dense_layer(
    char* __restrict__ hw, char* __restrict__ wbufs,
    const char* __restrict__ Wcur, const char* __restrict__ Wnext0,
    const char* __restrict__ Wnext1, const float* __restrict__ bias,
    i32x4 (&sreg)[4], int tid, int l, int hi)
{
    bf16x8 hf[2][16];                      // this wave's 64-sample h, all K=256
#pragma unroll
    for (int t = 0; t < 2; ++t)
#pragma unroll
        for (int kt = 0; kt < 16; ++kt)
            hf[t][kt] = *(const bf16x8*)(hw + t * 16384 + kt * 1024 + l * 16);

    for (int st = 0; st < 8; ++st) {
        char* A = wbufs + (st & 1) * 16384;         // live tile (nt = st)
        char* B = wbufs + ((st + 1) & 1) * 16384;   // idle buffer
        // write staged regs (tile st+1) into B; overlaps other waves' MFMA on A
#pragma unroll
        for (int j = 0; j < 4; ++j)
            *(i32x4*)(B + j * 4096 + tid * 16) = sreg[j];
        // issue global loads for tile st+2 (L2-resident; ~1 tile-window in flight)
        const char* nsrc = (st < 6) ? (Wcur + (st + 2) * 16384)
                                    : ((st == 6) ? Wnext0 : Wnext1);
#pragma unroll
        for (int j = 0; j < 4; ++j)
            sreg[j] = *(const i32x4*)(nsrc + j * 4096 + tid * 16);

        // MFMA on A: 2 sample-tiles x 16 kt; 4 independent acc chains
        f32x16 a00 = {}, a01 = {}, a10 = {}, a11 = {};
#pragma unroll
        for (int kk = 0; kk < 8; ++kk) {
            bf16x8 w0 = *(const bf16x8*)(A + (2 * kk    ) * 1024 + l * 16);
            bf16x8 w1 = *(const bf16x8*)(A + (2 * kk + 1) * 1024 + l * 16);
            a00 = __builtin_amdgcn_mfma_f32_32x32x16_bf16(w0, hf[0][2 * kk    ], a00, 0, 0, 0);
            a10 = __builtin_amdgcn_mfma_f32_32x32x16_bf16(w0, hf[1][2 * kk    ], a10, 0, 0, 0);
            a01 = __builtin_amdgcn_mfma_f32_32x32x16_bf16(w1, hf[0][2 * kk + 1], a01, 0, 0, 0);
            a11 = __builtin_amdgcn_mfma_f32_32x32x16_bf16(w1, hf[1][2 * kk + 1], a11, 0, 0, 0);
        }
        // bias + relu + bf16 pack + repack into next layer's B-fragment slots.
        // D layout (HW-verified m74/m101): col = lane&31 (sample),
        // row = (reg&3) + 8*(reg>>2) + 4*(lane>>5).  n = st*32 + row.
        int nt = st;
#pragma unroll
        for (int t = 0; t < 2; ++t) {
            f32x16 Aa = (t ? a10 : a00) + (t ? a11 : a01);
#pragma unroll
            for (int q = 0; q < 4; ++q) {
                f32x4 bb = *(const f32x4*)(bias + nt * 32 + 8 * q + 4 * hi);
                float v0 = fmaxf(Aa[4 * q + 0] + bb[0], 0.0f);
                float v1 = fmaxf(Aa[4 * q + 1] + bb[1], 0.0f);
                float v2 = fmaxf(Aa[4 * q + 2] + bb[2], 0.0f);
                float v3 = fmaxf(Aa[4 * q + 3] + bb[3], 0.0f);
                i32x2 pk;
                pk[0] = (int)f2bf(v0) | ((int)f2bf(v1) << 16);
                pk[1] = (int)f2bf(v2) | ((int)f2bf(v3) << 16);
                // dest: kt' = nt*2 + (q>>1); lane' = (l&31) + 32*(q&1); elems 4*hi..
                *(i32x2*)(hw + t * 16384 + (nt * 2 + (q >> 1)) * 1024 +
                          ((l & 31) + 32 * (q & 1)) * 16 + 8 * hi) = pk;
            }
        }
        __syncthreads();   // A fully consumed by all waves; B fully staged
    }
}

__launch_bounds__(256, 1)
__global__ void nerf_fused(
    const float* __restrict__ origins, const float* __restrict__ dirs,
    const float* __restrict__ W1, const float* __restrict__ b1,
    const float* __restrict__ b2, const float* __restrict__ b3,
    const float* __restrict__ b4,
    const unsigned* __restrict__ nearp, const unsigned* __restrict__ farp,
    const unsigned short* __restrict__ W2p, const unsigned short* __restrict__ W3p,
    const unsigned short* __restrict__ W4p,
    float* __restrict__ out)
{
    extern __shared__ char lds[];
    char* hall  = lds;             // 4 waves x 32KB h fragments
    char* wbufs = lds + 131072;    // 2 x 16KB weight stage (double buffer)

    const int tid = threadIdx.x;
    const int w   = tid >> 6;
    const int l   = tid & 63;
    const int hi  = l >> 5;
    char* hw = hall + w * 32768;
    const long ray = (long)blockIdx.x * 4 + w;

    const float nearv = decode_scalar(nearp);
    const float farv  = decode_scalar(farp);
    const float delta = (farv - nearv) * (1.0f / 64.0f);

    // ---- prologue: issue W2 tile0 + tile1 loads (latency hides under layer 1) ----
    i32x4 t0[4];
    i32x4 sreg[4];
#pragma unroll
    for (int j = 0; j < 4; ++j)
        t0[j] = *(const i32x4*)((const char*)W2p + j * 4096 + tid * 16);
#pragma unroll
    for (int j = 0; j < 4; ++j)
        sreg[j] = *(const i32x4*)((const char*)W2p + 16384 + j * 4096 + tid * 16);

    // ---- layer 1: h1 = relu((o@W1+b1) + z*(d@W1)), fp32 then bf16 pack ----
    // owdw scratch lives in wbuf1 (wave-private slice; consumed before st=0 writes it)
    float* owdw = (float*)(wbufs + 16384) + w * 512;
    {
        float o0 = origins[ray * 3 + 0], o1 = origins[ray * 3 + 1], o2 = origins[ray * 3 + 2];
        float d0 = dirs[ray * 3 + 0],    d1 = dirs[ray * 3 + 1],    d2 = dirs[ray * 3 + 2];
        int n0 = l * 4;
        f32x4 wa = *(const f32x4*)(W1 + n0);
        f32x4 wb = *(const f32x4*)(W1 + 256 + n0);
        f32x4 wc = *(const f32x4*)(W1 + 512 + n0);
        f32x4 bb = *(const f32x4*)(b1 + n0);
        f32x4 ow, dw;
#pragma unroll
        for (int e = 0; e < 4; ++e) {
            ow[e] = fmaf(o2, wc[e], fmaf(o1, wb[e], fmaf(o0, wa[e], bb[e])));
            dw[e] = fmaf(d2, wc[e], fmaf(d1, wb[e], d0 * wa[e]));
        }
        *(f32x4*)(owdw + n0) = ow;
        *(f32x4*)(owdw + 256 + n0) = dw;
    }
    // same-wave LDS RAW; compiler inserts lgkmcnt waits. Reads are half-wave broadcasts.
#pragma unroll
    for (int t = 0; t < 2; ++t) {
        float s = (float)(t * 32 + (l & 31));
        float z = nearv + (farv - nearv) * (s + 0.5f) * 0.015625f;
#pragma unroll
        for (int kt = 0; kt < 16; ++kt) {
            int k0 = kt * 16 + 8 * hi;
            f32x4 oa = *(const f32x4*)(owdw + k0);
            f32x4 ob = *(const f32x4*)(owdw + k0 + 4);
            f32x4 da = *(const f32x4*)(owdw + 256 + k0);
            f32x4 db = *(const f32x4*)(owdw + 256 + k0 + 4);
            float v0, v1;
            i32x4 pk;
            v0 = fmaxf(fmaf(z, da[0], oa[0]), 0.f); v1 = fmaxf(fmaf(z, da[1], oa[1]), 0.f);
            pk[0] = (int)f2bf(v0) | ((int)f2bf(v1) << 16);
            v0 = fmaxf(fmaf(z, da[2], oa[2]), 0.f); v1 = fmaxf(fmaf(z, da[3], oa[3]), 0.f);
            pk[1] = (int)f2bf(v0) | ((int)f2bf(v1) << 16);
            v0 = fmaxf(fmaf(z, db[0], ob[0]), 0.f); v1 = fmaxf(fmaf(z, db[1], ob[1]), 0.f);
            pk[2] = (int)f2bf(v0) | ((int)f2bf(v1) << 16);
            v0 = fmaxf(fmaf(z, db[2], ob[2]), 0.f); v1 = fmaxf(fmaf(z, db[3], ob[3]), 0.f);
            pk[3] = (int)f2bf(v0) | ((int)f2bf(v1) << 16);
            *(i32x4*)(hw + t * 16384 + kt * 1024 + l * 16) = pk;
        }
    }

    // stage W2 tile0 into buf0 (vmcnt wait covers the t0 loads)
#pragma unroll
    for (int j = 0; j < 4; ++j)
        *(i32x4*)(wbufs + j * 4096 + tid * 16) = t0[j];
    __syncthreads();   // buf0 visible; all waves' layer-1/owdw complete

    // ---- layers 2, 3 (17-tile chained pipeline) ----
    dense_layer(hw, wbufs, (const char*)W2p, (const char*)W3p,
                (const char*)W3p + 16384, b2, sreg, tid, l, hi);
    dense_layer(hw, wbufs, (const char*)W3p, (const char*)W4p,
                (const char*)W4p, b3, sreg, tid, l, hi);
    // buf0 now holds the W4 fragment tile; sreg holds a dummy (never written)

    // ---- layer 4: 256 -> 4 (padded to 32 rows) ----
    {
        bf16x8 hf[2][16];
#pragma unroll
        for (int t = 0; t < 2; ++t)
#pragma unroll
            for (int kt = 0; kt < 16; ++kt)
                hf[t][kt] = *(const bf16x8*)(hw + t * 16384 + kt * 1024 + l * 16);
        f32x16 a00 = {}, a01 = {}, a10 = {}, a11 = {};
#pragma unroll
        for (int kk = 0; kk < 8; ++kk) {
            bf16x8 w0 = *(const bf16x8*)(wbufs + (2 * kk    ) * 1024 + l * 16);
            bf16x8 w1 = *(const bf16x8*)(wbufs + (2 * kk + 1) * 1024 + l * 16);
            a00 = __builtin_amdgcn_mfma_f32_32x32x16_bf16(w0, hf[0][2 * kk    ], a00, 0, 0, 0);
            a10 = __builtin_amdgcn_mfma_f32_32x32x16_bf16(w0, hf[1][2 * kk    ], a10, 0, 0, 0);
            a01 = __builtin_amdgcn_mfma_f32_32x32x16_bf16(w1, hf[0][2 * kk + 1], a01, 0, 0, 0);
            a11 = __builtin_amdgcn_mfma_f32_32x32x16_bf16(w1, hf[1][2 * kk + 1], a11, 0, 0, 0);
        }
        // rows 0..3 (r,g,b,sigma) live in lanes 0..31, regs 0..3
        if (l < 32) {
            float bb0 = b4[0], bb1 = b4[1], bb2 = b4[2], bb3 = b4[3];
#pragma unroll
            for (int t = 0; t < 2; ++t) {
                f32x16 Aa = (t ? a10 : a00) + (t ? a11 : a01);
                float rr = Aa[0] + bb0, gg = Aa[1] + bb1;
                float bl = Aa[2] + bb2, sg = Aa[3] + bb3;
                float alpha = 1.0f - __expf(-fmaxf(sg, 0.0f) * delta);
                f32x4 cv;
                cv[0] = 1.0f / (1.0f + __expf(-rr));
                cv[1] = 1.0f / (1.0f + __expf(-gg));
                cv[2] = 1.0f / (1.0f + __expf(-bl));
                cv[3] = alpha;
                *(f32x4*)(hw + (t * 32 + l) * 16) = cv;   // hw is dead; wave-private
            }
        }
        asm volatile("s_waitcnt lgkmcnt(0)" ::: "memory");
    }

    // ---- composite (wave-private, sample = lane) ----
    {
        f32x4 cv = *(const f32x4*)(hw + l * 16);
        float alpha = cv[3];
        float p = 1.0f - alpha + 1e-10f;
        float P = p;                        // inclusive cumprod across 64 lanes
#pragma unroll
        for (int d = 1; d < 64; d <<= 1) {
            float u = __shfl_up(P, d, 64);
            if (l >= d) P *= u;
        }
        float T = __shfl_up(P, 1, 64);      // exclusive
        if (l == 0) T = 1.0f;
        float wt = alpha * T;
        float cr = wt * cv[0], cg = wt * cv[1], cb = wt * cv[2];
#pragma unroll
        for (int d = 32; d >= 1; d >>= 1) {
            cr += __shfl_down(cr, d, 64);
            cg += __shfl_down(cg, d, 64);
            cb += __shfl_down(cb, d, 64);
        }
        if (l == 0) {
            out[ray * 3 + 0] = cr;
            out[ray * 3 + 1] = cg;
            out[ray * 3 + 2] = cb;
        }
    }
}

extern "C" void kernel_launch(void* const* d_in, const int* in_sizes, int n_in,
                              void* d_out, int out_size, void* d_ws, size_t ws_size,
                              hipStream_t stream) {
    const float* origins = (const float*)d_in[0];
    const float* dirs    = (const float*)d_in[1];
    const float* W1 = (const float*)d_in[2];
    const float* b1 = (const float*)d_in[3];
    const float* W2 = (const float*)d_in[4];
    const float* b2 = (const float*)d_in[5];
    const float* W3 = (const float*)d_in[6];
    const float* b3 = (const float*)d_in[7];
    const float* W4 = (const float*)d_in[8];
    const float* b4 = (const float*)d_in[9];
    const unsigned* nearp = (const unsigned*)d_in[10];
    const unsigned* farp  = (const unsigned*)d_in[11];
    float* out = (float*)d_out;

    unsigned short* W2p = (unsigned short*)d_ws;          // 128KB
    unsigned short* W3p = W2p + 65536;                    // 128KB
    unsigned short* W4p = W2p + 131072;                   // 16KB

    hipFuncSetAttribute(reinterpret_cast<const void*>(nerf_fused),
                        hipFuncAttributeMaxDynamicSharedMemorySize, 163840);

    prep_pack<<<288, 256, 0, stream>>>(W2, W3, W4, W2p, W3p, W4p);
    nerf_fused<<<4096, 256, 163840, stream>>>(origins, dirs, W1, b1, b2, b3, b4,
                                              nearp, farp, W2p, W3p, W4p, out);
}

// Round 3
// 355.940 us; speedup vs baseline: 1.4613x; 1.4613x over previous
//
#include <hip/hip_runtime.h>

// NeRF fused render, MI355X. 16384 rays x 64 samples, MLP 3->256->256->256->4.
// R3 structure: 1 wave = 32 samples (half ray); block = 4 waves = 2 rays; grid 8192.
// Activations live ENTIRELY in registers (hf[16]/hg[16], 64 VGPR each); the
// D->next-layer-B repack is done in-register via v_permlane32_swap_b32 (verified
// equivalent to the LDS repack that passed in round 2). Weights staged to LDS via
// async global_load_lds (2x16KB double buffer). LDS = 32KB -> 2 blocks/CU ->
// 2 waves/SIMD so LDS-reads/VALU of one wave overlap MFMA of the other.

#define HID 256

typedef short bf16x8 __attribute__((ext_vector_type(8)));
typedef float f32x4  __attribute__((ext_vector_type(4)));
typedef float f32x16 __attribute__((ext_vector_type(16)));
typedef int   i32x4  __attribute__((ext_vector_type(4)));
typedef int   i32x2v __attribute__((ext_vector_type(2)));

static __device__ __forceinline__ unsigned short f2bf(float f) {
    unsigned u = __float_as_uint(f);
    u += 0x7fffu + ((u >> 16) & 1u);   // RNE
    return (unsigned short)(u >> 16);
}

// Fragment order (round-2-validated): [nt][kt 16][lane 64][e 8],
// element = W[k = kt*16 + 8*(lane>>5) + e][n = nt*32 + (lane&31)].
__global__ void prep_pack(const float* __restrict__ W2, const float* __restrict__ W3,
                          const float* __restrict__ W4,
                          unsigned short* __restrict__ W2p, unsigned short* __restrict__ W3p,
                          unsigned short* __restrict__ W4p) {
    int t = blockIdx.x * 256 + threadIdx.x;
    if (t < 65536) {
        int e  = t & 7;
        int l  = (t >> 3) & 63;
        int kt = (t >> 9) & 15;
        int nt = t >> 13;
        int k = kt * 16 + 8 * (l >> 5) + e;
        int n = nt * 32 + (l & 31);
        W2p[t] = f2bf(W2[k * HID + n]);
        W3p[t] = f2bf(W3[k * HID + n]);
    } else if (t < 65536 + 8192) {
        int u  = t - 65536;
        int e  = u & 7;
        int l  = (u >> 3) & 63;
        int kt = u >> 9;
        int k = kt * 16 + 8 * (l >> 5) + e;
        int n = l & 31;                        // cols 0..3 real, 4..31 zero pad
        W4p[u] = f2bf((n < 4) ? W4[k * 4 + n] : 0.0f);
    }
}

static __device__ __forceinline__ float decode_scalar(const unsigned* __restrict__ p) {
    unsigned w0 = p[0];
    if (w0 == 0u) {
        unsigned w1 = p[1];
        if (w1 != 0u) return (float)__hiloint2double((int)w1, (int)w0);
        return 0.0f;
    }
    if (w0 < 0x00800000u) return (float)(int)w0;   // small int
    return __uint_as_float(w0);                    // float32 bits
}

static __device__ __forceinline__ unsigned cvt_pk_bf16(float lo, float hi) {
    unsigned r;
    asm("v_cvt_pk_bf16_f32 %0, %1, %2" : "=v"(r) : "v"(lo), "v"(hi));
    return r;
}

static __device__ __forceinline__ void gload_lds16(const char* g, char* l) {
    __builtin_amdgcn_global_load_lds(
        (const __attribute__((address_space(1))) void*)g,
        (__attribute__((address_space(3))) void*)l, 16, 0, 0);
}

// One 256->256 layer: 8 output n-tiles (st), fully unrolled so all register
// indices are static. Per st: issue async loads of next chain tile into the idle
// buffer, 16 MFMAs (2 acc chains) on the live buffer, bias+relu+cvt_pk+permlane
// repack into o[2st],o[2st+1], one barrier.
template<int BASE>
static __device__ __forceinline__ void dense_layer(
    const bf16x8 (&h)[16], bf16x8 (&o)[16], char* __restrict__ wlds,
    const char* __restrict__ W2p, const char* __restrict__ W3p,
    const char* __restrict__ W4p, const float* __restrict__ bias,
    int tid, int l, int hi)
{
#pragma unroll
    for (int st = 0; st < 8; ++st) {
        const int gi = BASE + st;                       // global chain index 0..15
        char* live = wlds + (gi & 1) * 16384;
        char* idle = wlds + ((gi + 1) & 1) * 16384;
        const int ni = gi + 1;                          // next tile: W2 x8, W3 x8, W4
        const char* nsrc = (ni < 8) ? (W2p + ni * 16384)
                         : (ni < 16 ? (W3p + (ni - 8) * 16384) : W4p);
#pragma unroll
        for (int j = 0; j < 4; ++j)
            gload_lds16(nsrc + j * 4096 + tid * 16, idle + j * 4096 + tid * 16);

        f32x16 aA = {}, aB = {};
#pragma unroll
        for (int kk = 0; kk < 16; kk += 2) {
            bf16x8 w0 = *(const bf16x8*)(live + kk * 1024 + l * 16);
            bf16x8 w1 = *(const bf16x8*)(live + (kk + 1) * 1024 + l * 16);
            aA = __builtin_amdgcn_mfma_f32_32x32x16_bf16(w0, h[kk],     aA, 0, 0, 0);
            aB = __builtin_amdgcn_mfma_f32_32x32x16_bf16(w1, h[kk + 1], aB, 0, 0, 0);
        }
        // D (verified m74/m101 + round-2 pass): col = lane&31 = sample,
        // row n_local(r) = (r&3) + 8*(r>>2) + 4*hi.
        unsigned qw[4][2];
#pragma unroll
        for (int q = 0; q < 4; ++q) {
            f32x4 bb = *(const f32x4*)(bias + st * 32 + 8 * q + 4 * hi);
            float v0 = fmaxf(aA[4*q+0] + aB[4*q+0] + bb[0], 0.0f);
            float v1 = fmaxf(aA[4*q+1] + aB[4*q+1] + bb[1], 0.0f);
            float v2 = fmaxf(aA[4*q+2] + aB[4*q+2] + bb[2], 0.0f);
            float v3 = fmaxf(aA[4*q+3] + aB[4*q+3] + bb[3], 0.0f);
            qw[q][0] = cvt_pk_bf16(v0, v1);
            qw[q][1] = cvt_pk_bf16(v2, v3);
        }
        // permlane32_swap: r0 = {a.lo32, b.lo32}, r1 = {a.hi32, b.hi32}.
        // (q0,q1) -> o[2st] words {j, j+2}; (q2,q3) -> o[2st+1]. Equivalent to the
        // round-2 LDS repack mapping (own-q0/partner-q1 | partner-q0/own-q1).
#pragma unroll
        for (int j = 0; j < 2; ++j) {
            i32x2v r = __builtin_amdgcn_permlane32_swap((int)qw[0][j], (int)qw[1][j], false, false);
            i32x2v s = __builtin_amdgcn_permlane32_swap((int)qw[2][j], (int)qw[3][j], false, false);
            ((i32x4&)o[2*st  ])[j]     = r[0];
            ((i32x4&)o[2*st  ])[j + 2] = r[1];
            ((i32x4&)o[2*st+1])[j]     = s[0];
            ((i32x4&)o[2*st+1])[j + 2] = s[1];
        }
        __syncthreads();   // live fully consumed by all waves; idle loads drained
    }
}

__launch_bounds__(256, 2)
__global__ void nerf_fused(
    const float* __restrict__ origins, const float* __restrict__ dirs,
    const float* __restrict__ W1, const float* __restrict__ b1,
    const float* __restrict__ b2, const float* __restrict__ b3,
    const float* __restrict__ b4,
    const unsigned* __restrict__ nearp, const unsigned* __restrict__ farp,
    const unsigned short* __restrict__ W2p_, const unsigned short* __restrict__ W3p_,
    const unsigned short* __restrict__ W4p_,
    float* __restrict__ out)
{
    __shared__ char wlds[32768];                // 2 x 16KB weight double-buffer
    const int tid  = threadIdx.x;
    const int w    = tid >> 6;
    const int l    = tid & 63;
    const int hi   = l >> 5;
    const int half = w & 1;                     // which 32 samples of the ray
    const int rloc = w >> 1;                    // ray within block (0/1)
    const long ray = (long)blockIdx.x * 2 + rloc;
    const char* W2p = (const char*)W2p_;
    const char* W3p = (const char*)W3p_;
    const char* W4p = (const char*)W4p_;

    const float nearv = decode_scalar(nearp);
    const float farv  = decode_scalar(farp);
    const float delta = (farv - nearv) * (1.0f / 64.0f);

    // prologue: async-stage W2 tile0 -> buf0 (latency hides under layer 1)
#pragma unroll
    for (int j = 0; j < 4; ++j)
        gload_lds16(W2p + j * 4096 + tid * 16, wlds + j * 4096 + tid * 16);

    // ---- layer 1: h1 = relu((o@W1+b1) + z*(d@W1)); fp32, packed straight to regs.
    // owdw scratch in buf1 (consumed before st0's async loads target buf1).
    float* owdw = (float*)(wlds + 16384) + w * 512;
    {
        float o0 = origins[ray*3+0], o1 = origins[ray*3+1], o2 = origins[ray*3+2];
        float d0 = dirs[ray*3+0],    d1 = dirs[ray*3+1],    d2 = dirs[ray*3+2];
        int n0 = l * 4;
        f32x4 wa = *(const f32x4*)(W1 + n0);
        f32x4 wb = *(const f32x4*)(W1 + 256 + n0);
        f32x4 wc = *(const f32x4*)(W1 + 512 + n0);
        f32x4 bb = *(const f32x4*)(b1 + n0);
        f32x4 ow, dw;
#pragma unroll
        for (int e = 0; e < 4; ++e) {
            ow[e] = fmaf(o2, wc[e], fmaf(o1, wb[e], fmaf(o0, wa[e], bb[e])));
            dw[e] = fmaf(d2, wc[e], fmaf(d1, wb[e], d0 * wa[e]));
        }
        *(f32x4*)(owdw + n0) = ow;
        *(f32x4*)(owdw + 256 + n0) = dw;
    }
    bf16x8 hf[16], hg[16];
    {
        float s = (float)(half * 32 + (l & 31));
        float z = nearv + (farv - nearv) * (s + 0.5f) * 0.015625f;
#pragma unroll
        for (int kt = 0; kt < 16; ++kt) {
            int k0 = kt * 16 + 8 * hi;
            f32x4 oa = *(const f32x4*)(owdw + k0);
            f32x4 ob = *(const f32x4*)(owdw + k0 + 4);
            f32x4 da = *(const f32x4*)(owdw + 256 + k0);
            f32x4 db = *(const f32x4*)(owdw + 256 + k0 + 4);
            i32x4 pk;
            pk[0] = (int)cvt_pk_bf16(fmaxf(fmaf(z,da[0],oa[0]),0.f), fmaxf(fmaf(z,da[1],oa[1]),0.f));
            pk[1] = (int)cvt_pk_bf16(fmaxf(fmaf(z,da[2],oa[2]),0.f), fmaxf(fmaf(z,da[3],oa[3]),0.f));
            pk[2] = (int)cvt_pk_bf16(fmaxf(fmaf(z,db[0],ob[0]),0.f), fmaxf(fmaf(z,db[1],ob[1]),0.f));
            pk[3] = (int)cvt_pk_bf16(fmaxf(fmaf(z,db[2],ob[2]),0.f), fmaxf(fmaf(z,db[3],ob[3]),0.f));
            hf[kt] = (bf16x8&)pk;
        }
    }
    __syncthreads();   // buf0 staged (vmcnt drained by barrier); owdw consumed

    // ---- layers 2, 3 (17-tile async chain: W2 x8 -> W3 x8 -> W4) ----
    dense_layer<0>(hf, hg, wlds, W2p, W3p, W4p, b2, tid, l, hi);
    dense_layer<8>(hg, hf, wlds, W2p, W3p, W4p, b3, tid, l, hi);
    // W4 fragments now in buf0 (gi=16 even)

    // ---- layer 4: 256 -> 4 (padded to 32 rows) + sigmoid/alpha ----
    {
        f32x16 aA = {}, aB = {};
#pragma unroll
        for (int kk = 0; kk < 16; kk += 2) {
            bf16x8 w0 = *(const bf16x8*)(wlds + kk * 1024 + l * 16);
            bf16x8 w1 = *(const bf16x8*)(wlds + (kk + 1) * 1024 + l * 16);
            aA = __builtin_amdgcn_mfma_f32_32x32x16_bf16(w0, hf[kk],     aA, 0, 0, 0);
            aB = __builtin_amdgcn_mfma_f32_32x32x16_bf16(w1, hf[kk + 1], aB, 0, 0, 0);
        }
        // rows 0..3 (r,g,b,sigma) live in regs 0..3 of hi=0 lanes
        float* compf = (float*)(wlds + 16384);     // buf1 dead after st15 barrier
        if (l < 32) {
            float rr = aA[0] + aB[0] + b4[0];
            float gg = aA[1] + aB[1] + b4[1];
            float bl = aA[2] + aB[2] + b4[2];
            float sg = aA[3] + aB[3] + b4[3];
            float alpha = 1.0f - __expf(-fmaxf(sg, 0.0f) * delta);
            f32x4 cv;
            cv[0] = 1.0f / (1.0f + __expf(-rr));
            cv[1] = 1.0f / (1.0f + __expf(-gg));
            cv[2] = 1.0f / (1.0f + __expf(-bl));
            cv[3] = alpha;
            *(f32x4*)(compf + (rloc * 64 + half * 32 + l) * 4) = cv;
        }
    }
    __syncthreads();

    // ---- composite: wave 0 -> ray 0, wave 1 -> ray 1; lane = sample ----
    if (w < 2) {
        const float* compf = (const float*)(wlds + 16384);
        f32x4 cv = *(const f32x4*)(compf + (w * 64 + l) * 4);
        float alpha = cv[3];
        float p = 1.0f - alpha + 1e-10f;
        float P = p;                         // inclusive cumprod across 64 lanes
#pragma unroll
        for (int d = 1; d < 64; d <<= 1) {
            float u = __shfl_up(P, d, 64);
            if (l >= d) P *= u;
        }
        float T = __shfl_up(P, 1, 64);       // exclusive
        if (l == 0) T = 1.0f;
        float wt = alpha * T;
        float cr = wt * cv[0], cg = wt * cv[1], cb = wt * cv[2];
#pragma unroll
        for (int d = 32; d >= 1; d >>= 1) {
            cr += __shfl_down(cr, d, 64);
            cg += __shfl_down(cg, d, 64);
            cb += __shfl_down(cb, d, 64);
        }
        if (l == 0) {
            long rg = (long)blockIdx.x * 2 + w;
            out[rg * 3 + 0] = cr;
            out[rg * 3 + 1] = cg;
            out[rg * 3 + 2] = cb;
        }
    }
}

extern "C" void kernel_launch(void* const* d_in, const int* in_sizes, int n_in,
                              void* d_out, int out_size, void* d_ws, size_t ws_size,
                              hipStream_t stream) {
    const float* origins = (const float*)d_in[0];
    const float* dirs    = (const float*)d_in[1];
    const float* W1 = (const float*)d_in[2];
    const float* b1 = (const float*)d_in[3];
    const float* W2 = (const float*)d_in[4];
    const float* b2 = (const float*)d_in[5];
    const float* W3 = (const float*)d_in[6];
    const float* b3 = (const float*)d_in[7];
    const float* W4 = (const float*)d_in[8];
    const float* b4 = (const float*)d_in[9];
    const unsigned* nearp = (const unsigned*)d_in[10];
    const unsigned* farp  = (const unsigned*)d_in[11];
    float* out = (float*)d_out;

    unsigned short* W2p = (unsigned short*)d_ws;          // 128KB
    unsigned short* W3p = W2p + 65536;                    // 128KB
    unsigned short* W4p = W2p + 131072;                   // 16KB

    prep_pack<<<288, 256, 0, stream>>>(W2, W3, W4, W2p, W3p, W4p);
    nerf_fused<<<8192, 256, 0, stream>>>(origins, dirs, W1, b1, b2, b3, b4,
                                         nearp, farp, W2p, W3p, W4p, out);
}